// Round 10
// baseline (1186.839 us; speedup 1.0000x reference)
//
#include <hip/hip_runtime.h>
#include <hip/hip_bf16.h>
#include <stdint.h>

#define BATCH 8192
#define GROWS 9216          // >= 8192 + 7*127 padded rows
#define DIN   2048
#define DOUT  2048
#define NEXP  8
#define BM    128
#define BN    256
#define BK    32
#define NSLOT 72
#define BUFSZ 24576         // per K-tile buffer: A 8K + B 16K
#define BOFF  8192          // B region offset within buffer

typedef __attribute__((ext_vector_type(4))) float fx4;
typedef __attribute__((ext_vector_type(8))) short sx8;

__device__ __forceinline__ short f2b(float x){
  unsigned u = __float_as_uint(x);
  u = u + 0x7FFFu + ((u >> 16) & 1u);   // round-to-nearest-even
  return (short)(u >> 16);
}

__device__ __forceinline__ void gload16(const void* g, void* l){
  __builtin_amdgcn_global_load_lds(
      (const __attribute__((address_space(1))) unsigned int*)g,
      (__attribute__((address_space(3))) unsigned int*)l, 16, 0, 0);
}

// ---- K1: hetero {transw (8192 blocks)} || {count+LUT build (block 8192)} ----
// meta: [0..7] scatter cursors, [15] unused, [16] nslots, [17+s] slot expert
__global__ void k1_kernel(const float* __restrict__ W, short* __restrict__ Wt,
                          const int* __restrict__ actions, int* __restrict__ perm,
                          int* __restrict__ meta){
  __shared__ float tile[64][69];
  int t = threadIdx.x;   // 256
  if (blockIdx.x == 8192){
    int* cnt = (int*)tile;
    if (t < NEXP) cnt[t] = 0;
    for (int i = t; i < GROWS; i += 256) perm[i] = -1;
    __syncthreads();
    for (int i = t; i < BATCH; i += 256) atomicAdd(&cnt[actions[i]], 1);
    __syncthreads();
    if (t == 0){
      int s = 0, slot = 0;
      for (int e = 0; e < NEXP; ++e){
        meta[e] = s;                          // scatter cursor = segment start
        int ns = (cnt[e] + BM - 1) / BM;
        for (int q = 0; q < ns; ++q) meta[17 + slot++] = e;
        s += ns * BM;
      }
      meta[16] = slot;
    }
    return;
  }
  // transw: W[e][k][n] f32 -> Wt[e][n][k] bf16 (64x64 tiles)
  int id = blockIdx.x;
  int e  = id >> 10;
  int r2 = id & 1023;
  int k0 = (r2 >> 5) << 6;
  int n0 = (r2 & 31) << 6;
  const float* Wp = W + (size_t)e * DIN * DOUT + (size_t)k0 * DOUT + n0;
#pragma unroll
  for (int it = 0; it < 4; ++it){
    int r = it * 16 + (t >> 4);
    int c = (t & 15) * 4;
    fx4 v = *(const fx4*)(Wp + (size_t)r * DOUT + c);
    tile[r][c] = v.x; tile[r][c+1] = v.y; tile[r][c+2] = v.z; tile[r][c+3] = v.w;
  }
  __syncthreads();
  int n  = t >> 2;
  int kc = (t & 3) * 16;
  short vv[16];
#pragma unroll
  for (int j = 0; j < 16; ++j) vv[j] = f2b(tile[kc + j][n]);
  short* dst = Wt + (size_t)e * DOUT * DIN + (size_t)(n0 + n) * DIN + k0 + kc;
  *(sx8*)dst       = *(const sx8*)vv;
  *(sx8*)(dst + 8) = *(const sx8*)(vv + 8);
}

// ---- K2: scatter perm + metadata tail ----
__global__ void prep_scatter(const int* __restrict__ actions, const int* __restrict__ mxs,
                             int* __restrict__ perm, int* __restrict__ meta,
                             float* __restrict__ out){
  int i = blockIdx.x * 256 + threadIdx.x;
  if (i < BATCH){
    int e = actions[i];
    int p = atomicAdd(&meta[e], 1);
    perm[p] = i;
    out[(size_t)BATCH * DOUT + i]         = (float)mxs[i];
    out[(size_t)BATCH * DOUT + BATCH + i] = (float)actions[i];
  }
}

// ---- K3: gather + convert: xp[i][k] = bf16(xs[perm[i]][k]); pad rows -> 0 ----
__global__ void gatherx_kernel(const float* __restrict__ xs, const int* __restrict__ perm,
                               short* __restrict__ xp){
  int i = blockIdx.x;
  int t = threadIdx.x;
  short v[8];
  int p = perm[i];
  if (p >= 0){
    const fx4* src = (const fx4*)(xs + (size_t)p * DIN + t * 8);
    fx4 a = src[0], b2 = src[1];
    v[0]=f2b(a.x); v[1]=f2b(a.y); v[2]=f2b(a.z); v[3]=f2b(a.w);
    v[4]=f2b(b2.x); v[5]=f2b(b2.y); v[6]=f2b(b2.z); v[7]=f2b(b2.w);
  } else {
#pragma unroll
    for (int j = 0; j < 8; ++j) v[j] = 0;
  }
  *(sx8*)(xp + (size_t)i * DIN + t * 8) = *(const sx8*)v;
}

// ---- K4: grouped GEMM: 128x256xBK32, DOUBLE-buffer 48KB -> 3 blocks/CU, 1 round ----
__global__ __launch_bounds__(512, 6)
void moe_gemm_kernel(const short* __restrict__ xp, const short* __restrict__ Wt,
                     const float* __restrict__ bias, const int* __restrict__ perm,
                     const int* __restrict__ meta, float* __restrict__ out){
  __shared__ char lds[2 * BUFSZ];   // 48 KB

  int F = blockIdx.x;
  int slot = F >> 3, nb = F & 7;    // XCD = F%8 = nb -> B-panel L2 locality
  if (slot >= meta[16]) return;
  int e      = meta[17 + slot];
  int m_base = slot * BM;
  int n0     = nb * BN;

  int t    = threadIdx.x;
  int wid  = t >> 6;
  int l    = t & 63;
  int wm   = wid & 1;               // 2 wave rows
  int wn   = wid >> 1;              // 4 wave cols
  int lrow = l & 15;
  int lk   = l >> 4;

  // staging: LDS pos t*16 <-> (row, chunk) of row-pair-interleaved swizzled layout
  int srow = ((t >> 3) << 1) | ((t >> 2) & 1);
  int schk = (t & 3) ^ ((t >> 3) & 3);
  int ldst = t * 16;
  const char* ag  = (const char*)xp + ((size_t)(m_base + srow) * DIN + schk * 8) * 2;
  const char* bg0 = (const char*)Wt + (((size_t)e * DOUT + n0 + srow) * DIN + schk * 8) * 2;
  const char* bg1 = bg0 + (size_t)128 * DIN * 2;

  // fragment read addresses (same involution as staging)
  int arow = wm * 64 + lrow;
  int aline = arow >> 1;
  int addrA = aline * 128 + (arow & 1) * 64 + ((lk ^ (aline & 3)) << 4);
  int brow = wn * 64 + lrow;
  int bline = brow >> 1;
  int addrB = BOFF + bline * 128 + (brow & 1) * 64 + ((lk ^ (bline & 3)) << 4);

  fx4 acc[4][4];
#pragma unroll
  for (int m = 0; m < 4; ++m)
#pragma unroll
    for (int n = 0; n < 4; ++n)
      acc[m][n] = (fx4){0.f, 0.f, 0.f, 0.f};

  float bcol[4];
#pragma unroll
  for (int n = 0; n < 4; ++n)
    bcol[n] = bias[(size_t)e * DOUT + n0 + wn * 64 + n * 16 + lrow];

#define STAGE(kt, BASE) do{ \
    gload16(ag  + (size_t)(kt) * 64, lds + (BASE) + ldst); \
    gload16(bg0 + (size_t)(kt) * 64, lds + (BASE) + BOFF + ldst); \
    gload16(bg1 + (size_t)(kt) * 64, lds + (BASE) + BOFF + 8192 + ldst); \
  }while(0)

// min-2-phase step: stage next FIRST, then ds_read cur, MFMA, vmcnt(0)+barrier
#define KSTEP(CB, SB, DOSTG, kt) do{ \
    if (DOSTG) STAGE((kt) + 1, SB); \
    sx8 af[4], bf[4]; \
    _Pragma("unroll") for (int m = 0; m < 4; ++m) \
      af[m] = *(const sx8*)(lds + (CB) + addrA + m * 1024); \
    _Pragma("unroll") for (int n = 0; n < 4; ++n) \
      bf[n] = *(const sx8*)(lds + (CB) + addrB + n * 1024); \
    __builtin_amdgcn_s_setprio(1); \
    _Pragma("unroll") for (int m = 0; m < 4; ++m) \
    _Pragma("unroll") for (int n = 0; n < 4; ++n) \
      acc[m][n] = __builtin_amdgcn_mfma_f32_16x16x32_bf16(af[m], bf[n], acc[m][n], 0, 0, 0); \
    __builtin_amdgcn_s_setprio(0); \
    asm volatile("s_waitcnt vmcnt(0)" ::: "memory"); \
    __builtin_amdgcn_s_barrier(); \
    asm volatile("" ::: "memory"); \
  }while(0)

  // prologue: stage tile 0 -> buf0
  STAGE(0, 0);
  asm volatile("s_waitcnt vmcnt(0)" ::: "memory");
  __builtin_amdgcn_s_barrier();
  asm volatile("" ::: "memory");

  for (int kt = 0; kt < 62; kt += 2){
    KSTEP(0,     BUFSZ, 1, kt);       // compute buf0, stage kt+1 -> buf1
    KSTEP(BUFSZ, 0,     1, kt + 1);   // compute buf1, stage kt+2 -> buf0
  }
  KSTEP(0, BUFSZ, 1, 62);             // stages 63 -> buf1
  // step 63: compute only
  {
    sx8 af[4], bf[4];
#pragma unroll
    for (int m = 0; m < 4; ++m) af[m] = *(const sx8*)(lds + BUFSZ + addrA + m * 1024);
#pragma unroll
    for (int n = 0; n < 4; ++n) bf[n] = *(const sx8*)(lds + BUFSZ + addrB + n * 1024);
#pragma unroll
    for (int m = 0; m < 4; ++m)
#pragma unroll
      for (int n = 0; n < 4; ++n)
        acc[m][n] = __builtin_amdgcn_mfma_f32_16x16x32_bf16(af[m], bf[n], acc[m][n], 0, 0, 0);
  }

  // epilogue: scatter rows via perm, add bias
#pragma unroll
  for (int m = 0; m < 4; ++m){
    int rb = wm * 64 + m * 16 + lk * 4;
    int prow[4];
#pragma unroll
    for (int q = 0; q < 4; ++q)
      prow[q] = perm[m_base + rb + q];
#pragma unroll
    for (int n = 0; n < 4; ++n){
      int col = n0 + wn * 64 + n * 16 + lrow;
      fx4 v = acc[m][n];
#pragma unroll
      for (int q = 0; q < 4; ++q)
        if (prow[q] >= 0)
          out[(size_t)prow[q] * DOUT + col] = v[q] + bcol[n];
    }
  }
#undef KSTEP
#undef STAGE
}

extern "C" void kernel_launch(void* const* d_in, const int* in_sizes, int n_in,
                              void* d_out, int out_size, void* d_ws, size_t ws_size,
                              hipStream_t stream) {
  const float* xs      = (const float*)d_in[0];
  const float* W       = (const float*)d_in[1];
  const float* b       = (const float*)d_in[2];
  const int*   mxs     = (const int*)d_in[3];
  const int*   actions = (const int*)d_in[4];
  float* out = (float*)d_out;

  int*   perm = (int*)d_ws;                                   // GROWS ints
  int*   meta = (int*)((char*)d_ws + 40960);
  short* Wt   = (short*)((char*)d_ws + 65536);                // 64 MB bf16 W^T
  short* xp   = (short*)((char*)d_ws + 65536 + (size_t)NEXP * DIN * DOUT * 2); // 37.75 MB

  hipLaunchKernelGGL(k1_kernel, dim3(8193), dim3(256), 0, stream, W, Wt, actions, perm, meta);
  hipLaunchKernelGGL(prep_scatter, dim3(32), dim3(256), 0, stream, actions, mxs, perm, meta, out);
  hipLaunchKernelGGL(gatherx_kernel, dim3(GROWS), dim3(256), 0, stream, xs, perm, xp);
  hipLaunchKernelGGL(moe_gemm_kernel, dim3(NSLOT * 8), dim3(512), 0, stream,
                     xp, Wt, b, perm, meta, out);
}

// Round 11
// 188.376 us; speedup vs baseline: 6.3004x; 6.3004x over previous
//
#include <hip/hip_runtime.h>
#include <hip/hip_bf16.h>
#include <stdint.h>

#define BATCH 8192
#define GROWS 9216          // 72 slots x 128 rows
#define DIN   2048
#define DOUT  2048
#define NEXP  8
#define BM    128
#define BN    256
#define BK    32
#define BUFSZ 24576         // per K-tile buffer: A 8K + B 16K
#define BOFF  8192          // B region offset within buffer

typedef __attribute__((ext_vector_type(4))) float fx4;
typedef __attribute__((ext_vector_type(8))) short sx8;

__device__ __forceinline__ short f2b(float x){
  unsigned u = __float_as_uint(x);
  u = u + 0x7FFFu + ((u >> 16) & 1u);   // round-to-nearest-even
  return (short)(u >> 16);
}
__device__ __forceinline__ float b2f(short v){
  return __uint_as_float(((unsigned)(unsigned short)v) << 16);
}

__device__ __forceinline__ void gload16(const void* g, void* l){
  __builtin_amdgcn_global_load_lds(
      (const __attribute__((address_space(1))) unsigned int*)g,
      (__attribute__((address_space(3))) unsigned int*)l, 16, 0, 0);
}

// ---- K1: count + 128-aligned segments + slot->expert LUT + scatter + out tail ----
// meta: [0..7] scatter cursors, [16] nslots, [17+s] slot expert
__global__ void prep_kernel(const int* __restrict__ actions, const int* __restrict__ mxs,
                            int* __restrict__ perm, int* __restrict__ meta,
                            float* __restrict__ out){
  __shared__ int cnt[NEXP];
  int t = threadIdx.x;   // 1024
  if (t < NEXP) cnt[t] = 0;
  for (int i = t; i < GROWS; i += 1024) perm[i] = -1;
  __syncthreads();
  for (int i = t; i < BATCH; i += 1024) atomicAdd(&cnt[actions[i]], 1);
  __syncthreads();
  if (t == 0){
    int s = 0, slot = 0;
    for (int e = 0; e < NEXP; ++e){
      meta[e] = s;
      int ns = (cnt[e] + BM - 1) / BM;
      for (int q = 0; q < ns; ++q) meta[17 + slot++] = e;
      s += ns * BM;
    }
    meta[16] = slot;
  }
  __syncthreads();
  for (int i = t; i < BATCH; i += 1024){
    int e = actions[i];
    int p = atomicAdd(&meta[e], 1);
    perm[p] = i;
    out[(size_t)BATCH * DOUT + i]         = (float)mxs[i];
    out[(size_t)BATCH * DOUT + BATCH + i] = (float)actions[i];
  }
}

// ---- K2: hetero { transw (blocks 0..8191) || gather+convert (blocks 8192..) } ----
__global__ void k2_kernel(const float* __restrict__ W, short* __restrict__ Wt,
                          const float* __restrict__ xs, const int* __restrict__ perm,
                          short* __restrict__ xp){
  __shared__ float tile[64][69];
  int t = threadIdx.x;   // 256
  if (blockIdx.x >= 8192){
    int i = blockIdx.x - 8192;       // padded row
    short v[8];
    int p = perm[i];
    if (p >= 0){
      const fx4* src = (const fx4*)(xs + (size_t)p * DIN + t * 8);
      fx4 a = src[0], b2 = src[1];
      v[0]=f2b(a.x); v[1]=f2b(a.y); v[2]=f2b(a.z); v[3]=f2b(a.w);
      v[4]=f2b(b2.x); v[5]=f2b(b2.y); v[6]=f2b(b2.z); v[7]=f2b(b2.w);
    } else {
#pragma unroll
      for (int j = 0; j < 8; ++j) v[j] = 0;
    }
    *(sx8*)(xp + (size_t)i * DIN + t * 8) = *(const sx8*)v;
    return;
  }
  // transw: W[e][k][n] f32 -> Wt[e][n][k] bf16 (64x64 tiles)
  int id = blockIdx.x;
  int e  = id >> 10;
  int r2 = id & 1023;
  int k0 = (r2 >> 5) << 6;
  int n0 = (r2 & 31) << 6;
  const float* Wp = W + (size_t)e * DIN * DOUT + (size_t)k0 * DOUT + n0;
#pragma unroll
  for (int it = 0; it < 4; ++it){
    int r = it * 16 + (t >> 4);
    int c = (t & 15) * 4;
    fx4 v = *(const fx4*)(Wp + (size_t)r * DOUT + c);
    tile[r][c] = v.x; tile[r][c+1] = v.y; tile[r][c+2] = v.z; tile[r][c+3] = v.w;
  }
  __syncthreads();
  int n  = t >> 2;
  int kc = (t & 3) * 16;
  short vv[16];
#pragma unroll
  for (int j = 0; j < 16; ++j) vv[j] = f2b(tile[kc + j][n]);
  short* dst = Wt + (size_t)e * DOUT * DIN + (size_t)(n0 + n) * DIN + k0 + kc;
  *(sx8*)dst       = *(const sx8*)vv;
  *(sx8*)(dst + 8) = *(const sx8*)(vv + 8);
}

// ---- K3: grouped GEMM. Blocks 0..511: full items (R4-proven). 512..639: half-K tail ----
__global__ __launch_bounds__(512, 4)
void moe_gemm_kernel(const short* __restrict__ xp, const short* __restrict__ Wt,
                     const float* __restrict__ bias, const int* __restrict__ perm,
                     const int* __restrict__ meta, float* __restrict__ out,
                     short* __restrict__ tailbuf){
  __shared__ char lds[3 * BUFSZ];   // 72 KB -> 2 blocks/CU

  int nslots = meta[16];
  int F = blockIdx.x;
  int slot, nb, z = 0, h = 0, k0 = 0;
  bool tail = (F >= 512);
  if (!tail){ slot = F >> 3; nb = F & 7; }
  else { int j = F - 512; z = j >> 4; int rem = j & 15; nb = rem >> 1; h = rem & 1;
         slot = 64 + z; k0 = h * 32; }
  if (slot >= nslots) return;
  int e      = meta[17 + slot];
  int m_base = slot * BM;
  int n0     = nb * BN;

  int t    = threadIdx.x;
  int wid  = t >> 6;
  int l    = t & 63;
  int wm   = wid & 1;               // 2 wave rows
  int wn   = wid >> 1;              // 4 wave cols
  int lrow = l & 15;
  int lk   = l >> 4;

  // staging: LDS pos t*16 <-> (row, chunk) of row-pair-interleaved swizzled layout
  int srow = ((t >> 3) << 1) | ((t >> 2) & 1);
  int schk = (t & 3) ^ ((t >> 3) & 3);
  int ldst = t * 16;
  const char* ag  = (const char*)xp + ((size_t)(m_base + srow) * DIN + schk * 8) * 2;
  const char* bg0 = (const char*)Wt + (((size_t)e * DOUT + n0 + srow) * DIN + schk * 8) * 2;
  const char* bg1 = bg0 + (size_t)128 * DIN * 2;

  // fragment read addresses (same involution as staging)
  int arow = wm * 64 + lrow;
  int aline = arow >> 1;
  int addrA = aline * 128 + (arow & 1) * 64 + ((lk ^ (aline & 3)) << 4);
  int brow = wn * 64 + lrow;
  int bline = brow >> 1;
  int addrB = BOFF + bline * 128 + (brow & 1) * 64 + ((lk ^ (bline & 3)) << 4);

  fx4 acc[4][4];
#pragma unroll
  for (int m = 0; m < 4; ++m)
#pragma unroll
    for (int n = 0; n < 4; ++n)
      acc[m][n] = (fx4){0.f, 0.f, 0.f, 0.f};

#define STAGE(kt, BASE) do{ \
    gload16(ag  + (size_t)(kt) * 64, lds + (BASE) + ldst); \
    gload16(bg0 + (size_t)(kt) * 64, lds + (BASE) + BOFF + ldst); \
    gload16(bg1 + (size_t)(kt) * 64, lds + (BASE) + BOFF + 8192 + ldst); \
  }while(0)

#define KSTEP(CB, SB, DOSTG, kt) do{ \
    sx8 af[4], bf[4]; \
    _Pragma("unroll") for (int m = 0; m < 4; ++m) \
      af[m] = *(const sx8*)(lds + (CB) + addrA + m * 1024); \
    _Pragma("unroll") for (int n = 0; n < 4; ++n) \
      bf[n] = *(const sx8*)(lds + (CB) + addrB + n * 1024); \
    if (DOSTG) STAGE((kt) + 2, SB); \
    __builtin_amdgcn_s_setprio(1); \
    _Pragma("unroll") for (int m = 0; m < 4; ++m) \
    _Pragma("unroll") for (int n = 0; n < 4; ++n) \
      acc[m][n] = __builtin_amdgcn_mfma_f32_16x16x32_bf16(af[m], bf[n], acc[m][n], 0, 0, 0); \
    __builtin_amdgcn_s_setprio(0); \
    if (DOSTG) asm volatile("s_waitcnt vmcnt(3)" ::: "memory"); \
    else       asm volatile("s_waitcnt vmcnt(0)" ::: "memory"); \
    __builtin_amdgcn_s_barrier(); \
    asm volatile("" ::: "memory"); \
  }while(0)

  // prologue: stage tiles k0, k0+1
  STAGE(k0, 0);
  STAGE(k0 + 1, BUFSZ);
  asm volatile("s_waitcnt vmcnt(3)" ::: "memory");
  __builtin_amdgcn_s_barrier();
  asm volatile("" ::: "memory");

  if (!tail){
    float bcol[4];
#pragma unroll
    for (int n = 0; n < 4; ++n)
      bcol[n] = bias[(size_t)e * DOUT + n0 + wn * 64 + n * 16 + lrow];

    for (int kt = 0; kt < 60; kt += 3){
      KSTEP(0,         2*BUFSZ, 1, kt);
      KSTEP(BUFSZ,     0,       1, kt + 1);
      KSTEP(2*BUFSZ,   BUFSZ,   1, kt + 2);
    }
    KSTEP(0,       2*BUFSZ, 1, 60);
    KSTEP(BUFSZ,   0,       1, 61);
    KSTEP(2*BUFSZ, 0,       0, 62);
    {
      sx8 af[4], bf[4];
#pragma unroll
      for (int m = 0; m < 4; ++m) af[m] = *(const sx8*)(lds + addrA + m * 1024);
#pragma unroll
      for (int n = 0; n < 4; ++n) bf[n] = *(const sx8*)(lds + addrB + n * 1024);
#pragma unroll
      for (int m = 0; m < 4; ++m)
#pragma unroll
        for (int n = 0; n < 4; ++n)
          acc[m][n] = __builtin_amdgcn_mfma_f32_16x16x32_bf16(af[m], bf[n], acc[m][n], 0, 0, 0);
    }
    // epilogue: scatter rows via perm, add bias
#pragma unroll
    for (int m = 0; m < 4; ++m){
      int rb = wm * 64 + m * 16 + lk * 4;
      int prow[4];
#pragma unroll
      for (int q = 0; q < 4; ++q)
        prow[q] = perm[m_base + rb + q];
#pragma unroll
      for (int n = 0; n < 4; ++n){
        int col = n0 + wn * 64 + n * 16 + lrow;
        fx4 v = acc[m][n];
#pragma unroll
        for (int q = 0; q < 4; ++q)
          if (prow[q] >= 0)
            out[(size_t)prow[q] * DOUT + col] = v[q] + bcol[n];
      }
    }
  } else {
    // half-K: 32 tiles k0..k0+31
    for (int i = 0; i < 30; i += 3){
      KSTEP(0,         2*BUFSZ, 1, k0 + i);
      KSTEP(BUFSZ,     0,       1, k0 + i + 1);
      KSTEP(2*BUFSZ,   BUFSZ,   1, k0 + i + 2);
    }
    KSTEP(0, 0, 0, k0 + 30);   // vmcnt(0): tile k0+31 landed
    {
      sx8 af[4], bf[4];
#pragma unroll
      for (int m = 0; m < 4; ++m) af[m] = *(const sx8*)(lds + BUFSZ + addrA + m * 1024);
#pragma unroll
      for (int n = 0; n < 4; ++n) bf[n] = *(const sx8*)(lds + BUFSZ + addrB + n * 1024);
#pragma unroll
      for (int m = 0; m < 4; ++m)
#pragma unroll
        for (int n = 0; n < 4; ++n)
          acc[m][n] = __builtin_amdgcn_mfma_f32_16x16x32_bf16(af[m], bf[n], acc[m][n], 0, 0, 0);
    }
    // store bf16 partials: tailbuf[(h*8+z)*128 + r][nb*256 + col]
    short* base = tailbuf + ((size_t)(h * 8 + z) * 128) * DOUT;
#pragma unroll
    for (int m = 0; m < 4; ++m){
      int rb = wm * 64 + m * 16 + lk * 4;
#pragma unroll
      for (int n = 0; n < 4; ++n){
        int col = n0 + wn * 64 + n * 16 + lrow;
        fx4 v = acc[m][n];
#pragma unroll
        for (int q = 0; q < 4; ++q)
          base[(size_t)(rb + q) * DOUT + col] = f2b(v[q]);
      }
    }
  }
#undef KSTEP
#undef STAGE
}

// ---- K4: reduce tail halves + bias -> out (fixed order, deterministic) ----
__global__ void reduce_kernel(const short* __restrict__ tailbuf, const float* __restrict__ bias,
                              const int* __restrict__ perm, const int* __restrict__ meta,
                              float* __restrict__ out){
  int nslots = meta[16];
  int blk = blockIdx.x;          // z*128 + r
  int z = blk >> 7, r = blk & 127;
  int slot = 64 + z;
  if (slot >= nslots) return;
  int p = perm[slot * BM + r];
  if (p < 0) return;
  int e = meta[17 + slot];
  int c = threadIdx.x * 8;       // 256 thr x 8 cols
  const short* h0 = tailbuf + ((size_t)(z)     * 128 + r) * DOUT + c;
  const short* h1 = tailbuf + ((size_t)(8 + z) * 128 + r) * DOUT + c;
  sx8 a = *(const sx8*)h0;
  sx8 b = *(const sx8*)h1;
  const float* bs = bias + (size_t)e * DOUT + c;
  float o[8];
#pragma unroll
  for (int j = 0; j < 8; ++j) o[j] = b2f(a[j]) + b2f(b[j]) + bs[j];
  float* dst = out + (size_t)p * DOUT + c;
  *(fx4*)dst       = *(const fx4*)o;
  *(fx4*)(dst + 4) = *(const fx4*)(o + 4);
}

extern "C" void kernel_launch(void* const* d_in, const int* in_sizes, int n_in,
                              void* d_out, int out_size, void* d_ws, size_t ws_size,
                              hipStream_t stream) {
  const float* xs      = (const float*)d_in[0];
  const float* W       = (const float*)d_in[1];
  const float* b       = (const float*)d_in[2];
  const int*   mxs     = (const int*)d_in[3];
  const int*   actions = (const int*)d_in[4];
  float* out = (float*)d_out;

  int*   perm = (int*)d_ws;                                   // 36.9 KB
  int*   meta = (int*)((char*)d_ws + 40960);
  short* Wt   = (short*)((char*)d_ws + 65536);                // 64 MB bf16 W^T
  short* xp   = (short*)((char*)d_ws + 65536 + (size_t)NEXP * DIN * DOUT * 2);       // 37.75 MB
  short* tailbuf = (short*)((char*)xp + (size_t)GROWS * DIN * 2);                    // 8 MB

  hipLaunchKernelGGL(prep_kernel, dim3(1), dim3(1024), 0, stream, actions, mxs, perm, meta, out);
  hipLaunchKernelGGL(k2_kernel, dim3(8192 + GROWS), dim3(256), 0, stream, W, Wt, xs, perm, xp);
  hipLaunchKernelGGL(moe_gemm_kernel, dim3(640), dim3(512), 0, stream,
                     xp, Wt, b, perm, meta, out, tailbuf);
  hipLaunchKernelGGL(reduce_kernel, dim3(1024), dim3(256), 0, stream, tailbuf, b, perm, meta, out);
}